// Round 11
// baseline (994.375 us; speedup 1.0000x reference)
//
#include <hip/hip_runtime.h>
#include <hip/hip_bf16.h>

// 3-layer stacked LSTM forward (eval). Round 11 = Round 10 + ping-pong accs.
//  - Producer/consumer split kernel (32 blocks) kept from r10.
//  - NEW: two MFMA accumulator sets (A/B) aligned with the 2-step unroll:
//    gates for step t are read from set P while the t+1 x-side MFMA fills set Q.
//    Kills the WAR serialization (epilogue read -> xacc rewrite) that forced
//    h-MFMA -> epilogue -> x-MFMA into one serial chain per step.
//  - x-MFMA placed before the epilogue; afh ds_reads issued first.
//  - Publish cadence 16 steps (fewer bar_full drains).
//  - Math/accumulation order identical: absmax must stay exactly 0.001953125.
// T=512, B=256, IN=97(pad128), H1=128, H2=64, H3=1.

#define T_TOT 512
#define BB    256

typedef __attribute__((ext_vector_type(8))) short  short8v;   // 8 bf16
typedef __attribute__((ext_vector_type(4))) float  float4v;   // MFMA acc

__device__ __forceinline__ void bar_lds() {
    asm volatile("s_waitcnt lgkmcnt(0)\n\ts_barrier" ::: "memory");
}
__device__ __forceinline__ void bar_full() {
    asm volatile("s_waitcnt vmcnt(0) lgkmcnt(0)\n\ts_barrier" ::: "memory");
}

__device__ __forceinline__ float sigm(float x) {
    float e = __expf(-x);
    return __builtin_amdgcn_rcpf(1.0f + e);
}
__device__ __forceinline__ float tanh_(float x) {
    float e = __expf(2.0f * x);
    return 1.0f - 2.0f * __builtin_amdgcn_rcpf(1.0f + e);
}
__device__ __forceinline__ unsigned short f2bf(float x) {
    __hip_bfloat16 b = __float2bfloat16(x);
    return __builtin_bit_cast(unsigned short, b);
}

// ---------------------------------------------------------------------------
__global__ __launch_bounds__(256) void cvt_pad(
    const float* __restrict__ in, __hip_bfloat16* __restrict__ out, int R, int K)
{
    int total = R * 128;
    for (int idx = blockIdx.x * 256 + threadIdx.x; idx < total; idx += gridDim.x * 256) {
        int r = idx >> 7, c = idx & 127;
        float v = (c < K) ? in[(size_t)r * K + c] : 0.0f;
        out[idx] = __float2bfloat16(v);
    }
}
__global__ __launch_bounds__(256) void cvt_plain(
    const float* __restrict__ in, __hip_bfloat16* __restrict__ out, int n)
{
    int i = blockIdx.x * 256 + threadIdx.x;
    if (i < n) out[i] = __float2bfloat16(in[i]);
}
__global__ __launch_bounds__(256) void addvec(
    const float* __restrict__ a, const float* __restrict__ b, float* __restrict__ o, int n)
{
    int i = blockIdx.x * 256 + threadIdx.x;
    if (i < n) o[i] = a[i] + b[i];
}
__global__ void zero_flags(unsigned int* f) { f[threadIdx.x] = 0u; }

// ---------------------------------------------------------------------------
// Fused 3-layer kernel. 32 blocks x 512 threads.
// ---------------------------------------------------------------------------
__global__ __launch_bounds__(512, 2) void lstm_all(
    const __hip_bfloat16* __restrict__ xb,    // [T,BB,128]
    const __hip_bfloat16* __restrict__ Wx1,   // [512,128]
    const __hip_bfloat16* __restrict__ Wh1,   // [512,128]
    const float* __restrict__ bias1,          // [512]
    __hip_bfloat16* __restrict__ h1b,         // [T,BB,128]
    const __hip_bfloat16* __restrict__ Wx2,   // [256,128]
    const __hip_bfloat16* __restrict__ Wh2,   // [256,64]
    const float* __restrict__ bias2,          // [256]
    const float* __restrict__ Wx3,            // [4,64] f32
    const float* __restrict__ Wh3,            // [4,1]  f32
    const float* __restrict__ bias3,          // [4]
    float* __restrict__ out,                  // [T,BB]
    unsigned int* __restrict__ flags)         // [32]
{
    const int tid  = threadIdx.x;
    const int lane = tid & 63;
    const int wid  = tid >> 6;
    const int bid  = blockIdx.x;

    __shared__ __align__(16) char  hbP[2][4096];   // producer h ring (bf16, swz)
    __shared__ __align__(16) char  h2b[2][2048];   // consumer h2 ring (bf16, swz)
    __shared__ __align__(16) float h2f[2][16][68]; // consumer h2 ring (f32, for L3)
    __shared__ float g3[64];

    if (bid < 16) {
        // ================= PRODUCER: layer 1 =================
        const int br0 = bid * 16;
        const int myu = wid * 16 + (lane & 15);

        uint4 wfx[4][4], wfh[4][4];
        {
            const char* Wxg = (const char*)Wx1;
            const char* Whg = (const char*)Wh1;
#pragma unroll
            for (int G = 0; G < 4; ++G) {
                int row = G * 128 + myu;
#pragma unroll
                for (int kf = 0; kf < 4; ++kf) {
                    int colb = (kf * 32 + (lane >> 4) * 8) * 2;
                    wfx[G][kf] = *(const uint4*)(Wxg + (size_t)row * 256 + colb);
                    wfh[G][kf] = *(const uint4*)(Whg + (size_t)row * 256 + colb);
                }
            }
        }
#pragma unroll
        for (int G = 0; G < 4; ++G)
#pragma unroll
            for (int kf = 0; kf < 4; ++kf) {
                asm volatile("" : "+v"(wfx[G][kf].x), "+v"(wfx[G][kf].y),
                                  "+v"(wfx[G][kf].z), "+v"(wfx[G][kf].w));
                asm volatile("" : "+v"(wfh[G][kf].x), "+v"(wfh[G][kf].y),
                                  "+v"(wfh[G][kf].z), "+v"(wfh[G][kf].w));
            }

        float bv[4];
#pragma unroll
        for (int G = 0; G < 4; ++G) bv[G] = bias1[G * 128 + myu];
        float c[4] = {0.0f, 0.0f, 0.0f, 0.0f};

        ((unsigned int*)hbP)[tid]       = 0u;
        ((unsigned int*)hbP)[tid + 512] = 0u;

        int hrd[4];
#pragma unroll
        for (int kf = 0; kf < 4; ++kf) {
            int row = lane & 15;
            hrd[kf] = (row * 256 + kf * 64 + (lane >> 4) * 16) ^ ((row & 7) << 4);
        }
        int hwr[4];
#pragma unroll
        for (int r = 0; r < 4; ++r) {
            int br = (lane >> 4) * 4 + r;
            hwr[r] = (br * 256 + myu * 2) ^ ((br & 7) << 4);
        }
        const int row0 = tid >> 6;
        const int fl0  = (tid * 4) ^ ((row0 & 7) << 4);

        const char* xgb = (const char*)xb +
            ((size_t)(br0 + (lane & 15)) * 128 + (lane >> 4) * 8) * 2;
        const char* xp = xgb + 2 * 65536;
        char* hp = (char*)h1b + (size_t)(br0 + row0) * 256 + (tid & 63) * 4;

        __syncthreads();

        // prologue: xaccA = bias + x[0]*Wx ; xB <- x[1]
        uint4 xA[4], xB[4];
#pragma unroll
        for (int kf = 0; kf < 4; ++kf) xA[kf] = *(const uint4*)(xgb + kf * 64);
        float4v xaccA[4], xaccB[4];
#pragma unroll
        for (int G = 0; G < 4; ++G) {
            float4v a = {bv[G], bv[G], bv[G], bv[G]};
#pragma unroll
            for (int kf = 0; kf < 4; ++kf)
                a = __builtin_amdgcn_mfma_f32_16x16x32_bf16(
                    __builtin_bit_cast(short8v, xA[kf]),
                    __builtin_bit_cast(short8v, wfx[G][kf]), a, 0, 0, 0);
            xaccA[G] = a;
        }
#pragma unroll
        for (int kf = 0; kf < 4; ++kf) xB[kf] = *(const uint4*)(xgb + 65536 + kf * 64);

// PSTEP: gates from ACCG (in place), next-step x-acc into ACCN from XUSE,
// prefetch into XLOAD. ACCG/ACCN are distinct register sets -> epilogue(T)
// and x-MFMA(T+1) are independent; scheduler interleaves them.
#define PSTEP(T, CUR, ACCG, ACCN, XUSE, XLOAD) do {                            \
        short8v afh[4];                                                        \
        afh[0] = *(const short8v*)(&hbP[CUR][0] + hrd[0]);                     \
        afh[1] = *(const short8v*)(&hbP[CUR][0] + hrd[1]);                     \
        afh[2] = *(const short8v*)(&hbP[CUR][0] + hrd[2]);                     \
        afh[3] = *(const short8v*)(&hbP[CUR][0] + hrd[3]);                     \
        if ((T) > 0) {                                                         \
            unsigned int d0 = *(const unsigned int*)(&hbP[CUR][0] + fl0);      \
            unsigned int d1 = *(const unsigned int*)(&hbP[CUR][0] + fl0 + 2048);\
            *(unsigned int*)hp = d0;                                           \
            *(unsigned int*)(hp + 2048) = d1;                                  \
            hp += 65536;                                                       \
        }                                                                      \
        _Pragma("unroll")                                                      \
        for (int G = 0; G < 4; ++G)                                            \
            _Pragma("unroll")                                                  \
            for (int kf = 0; kf < 4; ++kf)                                     \
                ACCG[G] = __builtin_amdgcn_mfma_f32_16x16x32_bf16(             \
                    afh[kf], __builtin_bit_cast(short8v, wfh[G][kf]),          \
                    ACCG[G], 0, 0, 0);                                         \
        if ((T) + 1 < T_TOT) {                                                 \
            _Pragma("unroll")                                                  \
            for (int G = 0; G < 4; ++G) {                                      \
                float4v a = {bv[G], bv[G], bv[G], bv[G]};                      \
                _Pragma("unroll")                                              \
                for (int kf = 0; kf < 4; ++kf)                                 \
                    a = __builtin_amdgcn_mfma_f32_16x16x32_bf16(               \
                        __builtin_bit_cast(short8v, XUSE[kf]),                 \
                        __builtin_bit_cast(short8v, wfx[G][kf]), a, 0, 0, 0);  \
                ACCN[G] = a;                                                   \
            }                                                                  \
        }                                                                      \
        if ((T) + 2 < T_TOT) {                                                 \
            XLOAD[0] = *(const uint4*)(xp + 0);                                \
            XLOAD[1] = *(const uint4*)(xp + 64);                               \
            XLOAD[2] = *(const uint4*)(xp + 128);                              \
            XLOAD[3] = *(const uint4*)(xp + 192);                              \
            xp += 65536;                                                       \
        }                                                                      \
        _Pragma("unroll")                                                      \
        for (int r = 0; r < 4; ++r) {                                          \
            float i_ = sigm(ACCG[0][r]);                                       \
            float f_ = sigm(ACCG[1][r]);                                       \
            float g_ = tanh_(ACCG[2][r]);                                      \
            float o_ = sigm(ACCG[3][r]);                                       \
            c[r] = fmaf(f_, c[r], i_ * g_);                                    \
            float hv = o_ * tanh_(c[r]);                                       \
            *(unsigned short*)(&hbP[(CUR) ^ 1][0] + hwr[r]) = f2bf(hv);        \
        }                                                                      \
        bar_lds();                                                             \
    } while (0)

        for (int t0 = 0; t0 < T_TOT; t0 += 16) {
#pragma unroll
            for (int u = 0; u < 16; u += 2) {
                PSTEP(t0 + u,     0, xaccA, xaccB, xB, xA);
                PSTEP(t0 + u + 1, 1, xaccB, xaccA, xA, xB);
            }
            bar_full();
            if (tid == 0) {
                __threadfence();
                __hip_atomic_store(&flags[bid], (unsigned int)(t0 / 16 + 1),
                                   __ATOMIC_RELEASE, __HIP_MEMORY_SCOPE_AGENT);
            }
        }
        // final flush of step 511 (h state in hbP[0])
        {
            unsigned int d0 = *(const unsigned int*)(&hbP[0][0] + fl0);
            unsigned int d1 = *(const unsigned int*)(&hbP[0][0] + fl0 + 2048);
            *(unsigned int*)hp = d0;
            *(unsigned int*)(hp + 2048) = d1;
        }
        asm volatile("s_waitcnt vmcnt(0)" ::: "memory");
        __syncthreads();
        if (tid == 0) {
            __threadfence();
            __hip_atomic_store(&flags[bid], 1u << 20,
                               __ATOMIC_RELEASE, __HIP_MEMORY_SCOPE_AGENT);
        }
#undef PSTEP

    } else {
        // ================= CONSUMER: layers 2+3 =================
        const int cbid = bid - 16;
        const int br0  = cbid * 16;
        const int myu  = wid * 16 + (lane & 15);
        unsigned int* flagp = &flags[cbid];

        uint4 wfx2[4][4], wfh2[4][2];
        float bv2[4];
        float c2[4] = {0.0f, 0.0f, 0.0f, 0.0f};
        int hrd2[2], hwr2[4];
        float4 w3[16];
        float bv3 = 0.0f, c3 = 0.0f, h3 = 0.0f;
        float w30 = 0.0f, w31 = 0.0f, w32 = 0.0f, w33 = 0.0f;
        float* outp = out + br0 + lane;

        if (wid < 4) {
            const char* Wxg = (const char*)Wx2;
            const char* Whg = (const char*)Wh2;
#pragma unroll
            for (int G = 0; G < 4; ++G) {
                int row = G * 64 + myu;
#pragma unroll
                for (int kf = 0; kf < 4; ++kf)
                    wfx2[G][kf] = *(const uint4*)(Wxg + (size_t)row * 256 +
                                                  (kf * 32 + (lane >> 4) * 8) * 2);
#pragma unroll
                for (int kf = 0; kf < 2; ++kf)
                    wfh2[G][kf] = *(const uint4*)(Whg + (size_t)row * 128 +
                                                  (kf * 32 + (lane >> 4) * 8) * 2);
            }
#pragma unroll
            for (int G = 0; G < 4; ++G) {
#pragma unroll
                for (int kf = 0; kf < 4; ++kf)
                    asm volatile("" : "+v"(wfx2[G][kf].x), "+v"(wfx2[G][kf].y),
                                      "+v"(wfx2[G][kf].z), "+v"(wfx2[G][kf].w));
#pragma unroll
                for (int kf = 0; kf < 2; ++kf)
                    asm volatile("" : "+v"(wfh2[G][kf].x), "+v"(wfh2[G][kf].y),
                                      "+v"(wfh2[G][kf].z), "+v"(wfh2[G][kf].w));
            }
#pragma unroll
            for (int G = 0; G < 4; ++G) bv2[G] = bias2[G * 64 + myu];
#pragma unroll
            for (int kf = 0; kf < 2; ++kf) {
                int row = lane & 15;
                hrd2[kf] = (row * 128 + kf * 64 + (lane >> 4) * 16) ^ ((row & 7) << 4);
            }
#pragma unroll
            for (int r = 0; r < 4; ++r) {
                int br = (lane >> 4) * 4 + r;
                hwr2[r] = (br * 128 + myu * 2) ^ ((br & 7) << 4);
            }
        } else if (wid == 4) {
            const int gate = lane & 3;
            const float4* w3p = (const float4*)(Wx3 + gate * 64);
#pragma unroll
            for (int j = 0; j < 16; ++j) w3[j] = w3p[j];
            bv3 = bias3[gate];
            w30 = Wh3[0]; w31 = Wh3[1]; w32 = Wh3[2]; w33 = Wh3[3];
        }

        if (tid < 512) ((unsigned int*)h2b)[tid] = 0u;

        if (tid == 0) {
            while (__hip_atomic_load(flagp, __ATOMIC_ACQUIRE,
                                     __HIP_MEMORY_SCOPE_AGENT) * 16u < 16u)
                __builtin_amdgcn_s_sleep(16);
        }
        __syncthreads();
        __threadfence();

        const char* xgb = (const char*)h1b +
            ((size_t)(br0 + (lane & 15)) * 128 + (lane >> 4) * 8) * 2;
        const char* xp2 = xgb + 2 * 65536;
        uint4 xA[4], xB[4];
        float4v xacc2A[4], xacc2B[4];
        if (wid < 4) {
#pragma unroll
            for (int kf = 0; kf < 4; ++kf) xA[kf] = *(const uint4*)(xgb + kf * 64);
#pragma unroll
            for (int G = 0; G < 4; ++G) {
                float4v a = {bv2[G], bv2[G], bv2[G], bv2[G]};
#pragma unroll
                for (int kf = 0; kf < 4; ++kf)
                    a = __builtin_amdgcn_mfma_f32_16x16x32_bf16(
                        __builtin_bit_cast(short8v, xA[kf]),
                        __builtin_bit_cast(short8v, wfx2[G][kf]), a, 0, 0, 0);
                xacc2A[G] = a;
            }
#pragma unroll
            for (int kf = 0; kf < 4; ++kf) xB[kf] = *(const uint4*)(xgb + 65536 + kf * 64);
        }
        __syncthreads();

#define CSTEP(T, CUR, ACCG, ACCN, XUSE, XLOAD) do {                            \
        if (wid < 4) {                                                         \
            short8v afh2[2];                                                   \
            afh2[0] = *(const short8v*)(&h2b[CUR][0] + hrd2[0]);               \
            afh2[1] = *(const short8v*)(&h2b[CUR][0] + hrd2[1]);               \
            _Pragma("unroll")                                                  \
            for (int G = 0; G < 4; ++G)                                        \
                _Pragma("unroll")                                              \
                for (int kf = 0; kf < 2; ++kf)                                 \
                    ACCG[G] = __builtin_amdgcn_mfma_f32_16x16x32_bf16(         \
                        afh2[kf], __builtin_bit_cast(short8v, wfh2[G][kf]),    \
                        ACCG[G], 0, 0, 0);                                     \
            if ((T) + 1 < T_TOT) {                                             \
                _Pragma("unroll")                                              \
                for (int G = 0; G < 4; ++G) {                                  \
                    float4v a = {bv2[G], bv2[G], bv2[G], bv2[G]};              \
                    _Pragma("unroll")                                          \
                    for (int kf = 0; kf < 4; ++kf)                             \
                        a = __builtin_amdgcn_mfma_f32_16x16x32_bf16(           \
                            __builtin_bit_cast(short8v, XUSE[kf]),             \
                            __builtin_bit_cast(short8v, wfx2[G][kf]),          \
                            a, 0, 0, 0);                                       \
                    ACCN[G] = a;                                               \
                }                                                              \
            }                                                                  \
            if ((T) + 2 < T_TOT) {                                             \
                XLOAD[0] = *(const uint4*)(xp2 + 0);                           \
                XLOAD[1] = *(const uint4*)(xp2 + 64);                          \
                XLOAD[2] = *(const uint4*)(xp2 + 128);                         \
                XLOAD[3] = *(const uint4*)(xp2 + 192);                         \
                xp2 += 65536;                                                  \
            }                                                                  \
            _Pragma("unroll")                                                  \
            for (int r = 0; r < 4; ++r) {                                      \
                float i_ = sigm(ACCG[0][r]);                                   \
                float f_ = sigm(ACCG[1][r]);                                   \
                float g_ = tanh_(ACCG[2][r]);                                  \
                float o_ = sigm(ACCG[3][r]);                                   \
                c2[r] = fmaf(f_, c2[r], i_ * g_);                              \
                float hv = o_ * tanh_(c2[r]);                                  \
                *(unsigned short*)(&h2b[(CUR) ^ 1][0] + hwr2[r]) = f2bf(hv);   \
                h2f[(CUR) ^ 1][(lane >> 4) * 4 + r][myu] = hv;                 \
            }                                                                  \
        } else if (wid == 4) {                                                 \
            if ((T) >= 1) {                                                    \
                const float* hrow = &h2f[CUR][lane >> 2][0];                   \
                float a = bv3;                                                 \
                _Pragma("unroll")                                              \
                for (int j = 0; j < 16; ++j) {                                 \
                    float4 hv = ((const float4*)hrow)[j];                      \
                    float4 wv = w3[j];                                         \
                    a = fmaf(hv.x, wv.x, a);                                   \
                    a = fmaf(hv.y, wv.y, a);                                   \
                    a = fmaf(hv.z, wv.z, a);                                   \
                    a = fmaf(hv.w, wv.w, a);                                   \
                }                                                              \
                g3[lane] = a;                                                  \
                if (lane < 16) {                                               \
                    float4 gg = *(const float4*)(g3 + lane * 4);               \
                    float gi  = fmaf(h3, w30, gg.x);                           \
                    float gf  = fmaf(h3, w31, gg.y);                           \
                    float gg_ = fmaf(h3, w32, gg.z);                           \
                    float go  = fmaf(h3, w33, gg.w);                           \
                    float i_ = sigm(gi);                                       \
                    float f_ = sigm(gf);                                       \
                    float g_ = tanh_(gg_);                                     \
                    float o_ = sigm(go);                                       \
                    c3 = fmaf(f_, c3, i_ * g_);                                \
                    h3 = o_ * tanh_(c3);                                       \
                    *outp = h3;                                                \
                }                                                              \
                outp += BB;                                                    \
            }                                                                  \
        }                                                                      \
        bar_lds();                                                             \
    } while (0)

        for (int t0 = 0; t0 < T_TOT; t0 += 8) {
            if (t0 > 0) {
                if (tid == 0) {
                    unsigned int need = (unsigned int)(t0 + 16);
                    while (__hip_atomic_load(flagp, __ATOMIC_ACQUIRE,
                                             __HIP_MEMORY_SCOPE_AGENT) * 16u < need)
                        __builtin_amdgcn_s_sleep(16);
                }
                bar_lds();
                __threadfence();
            }
#pragma unroll
            for (int u = 0; u < 8; u += 2) {
                CSTEP(t0 + u,     0, xacc2A, xacc2B, xB, xA);
                CSTEP(t0 + u + 1, 1, xacc2B, xacc2A, xA, xB);
            }
        }
        // tail: L3 step for t=512 (reads h2f[0], written at t=511)
        if (wid == 4) {
            const float* hrow = &h2f[0][lane >> 2][0];
            float a = bv3;
#pragma unroll
            for (int j = 0; j < 16; ++j) {
                float4 hv = ((const float4*)hrow)[j];
                float4 wv = w3[j];
                a = fmaf(hv.x, wv.x, a);
                a = fmaf(hv.y, wv.y, a);
                a = fmaf(hv.z, wv.z, a);
                a = fmaf(hv.w, wv.w, a);
            }
            g3[lane] = a;
            if (lane < 16) {
                float4 gg = *(const float4*)(g3 + lane * 4);
                float gi  = fmaf(h3, w30, gg.x);
                float gf  = fmaf(h3, w31, gg.y);
                float gg_ = fmaf(h3, w32, gg.z);
                float go  = fmaf(h3, w33, gg.w);
                float i_ = sigm(gi);
                float f_ = sigm(gf);
                float g_ = tanh_(gg_);
                float o_ = sigm(go);
                c3 = fmaf(f_, c3, i_ * g_);
                h3 = o_ * tanh_(c3);
                *outp = h3;
            }
        }
#undef CSTEP
    }
}

// ---------------------------------------------------------------------------
extern "C" void kernel_launch(void* const* d_in, const int* in_sizes, int n_in,
                              void* d_out, int out_size, void* d_ws, size_t ws_size,
                              hipStream_t stream) {
    const float* x    = (const float*)d_in[0];
    const float* Wih1 = (const float*)d_in[1];
    const float* Whh1 = (const float*)d_in[2];
    const float* bih1 = (const float*)d_in[3];
    const float* bhh1 = (const float*)d_in[4];
    const float* Wih2 = (const float*)d_in[5];
    const float* Whh2 = (const float*)d_in[6];
    const float* bih2 = (const float*)d_in[7];
    const float* bhh2 = (const float*)d_in[8];
    const float* Wih3 = (const float*)d_in[9];
    const float* Whh3 = (const float*)d_in[10];
    const float* bih3 = (const float*)d_in[11];
    const float* bhh3 = (const float*)d_in[12];
    float* out = (float*)d_out;

    char* ws = (char*)d_ws;
    __hip_bfloat16* xb    = (__hip_bfloat16*)(ws + 0);          // 33,554,432
    __hip_bfloat16* h1b   = (__hip_bfloat16*)(ws + 33554432);   // 33,554,432
    __hip_bfloat16* wb1   = (__hip_bfloat16*)(ws + 67108864);   //    131,072
    __hip_bfloat16* whb1  = (__hip_bfloat16*)(ws + 67239936);   //    131,072
    __hip_bfloat16* wb2   = (__hip_bfloat16*)(ws + 67371008);   //     65,536
    __hip_bfloat16* whb2  = (__hip_bfloat16*)(ws + 67436544);   //     32,768
    float*          bias1 = (float*)(ws + 67469312);            //      2,048
    float*          bias2 = (float*)(ws + 67471360);            //      1,024
    float*          bias3 = (float*)(ws + 67472384);            //         64
    unsigned int*   flags = (unsigned int*)(ws + 67472448);     //        128

    zero_flags<<<1, 32, 0, stream>>>(flags);
    cvt_pad<<<4096, 256, 0, stream>>>(x, xb, T_TOT * BB, 97);
    cvt_pad<<<256, 256, 0, stream>>>(Wih1, wb1, 512, 97);
    cvt_plain<<<256, 256, 0, stream>>>(Whh1, whb1, 512 * 128);
    cvt_plain<<<128, 256, 0, stream>>>(Wih2, wb2, 256 * 128);
    cvt_plain<<<64, 256, 0, stream>>>(Whh2, whb2, 256 * 64);
    addvec<<<2, 256, 0, stream>>>(bih1, bhh1, bias1, 512);
    addvec<<<1, 256, 0, stream>>>(bih2, bhh2, bias2, 256);
    addvec<<<1, 256, 0, stream>>>(bih3, bhh3, bias3, 4);

    lstm_all<<<32, 512, 0, stream>>>(
        xb, wb1, whb1, bias1, h1b,
        wb2, whb2, bias2, Wih3, Whh3, bias3, out, flags);
}

// Round 12
// 914.422 us; speedup vs baseline: 1.0874x; 1.0874x over previous
//
#include <hip/hip_runtime.h>
#include <hip/hip_bf16.h>

// 3-layer stacked LSTM forward (eval). Round 12: back to FULL-CHIP VALU scans.
//  Trajectory evidence: r6's 256-block dot2 scan did 1988 cyc/step WITH a
//  weight-spill refetch (FETCH 33MB, VGPR=44: compiler sank the 64-VGPR weight
//  array because __launch_bounds__(512) w/o min-waves targets 8 waves/EU).
//  The r7-r11 MFMA scans (16 blocks) never beat 3150 cyc/step - structurally
//  capped at 1/16 of the chip. Fix r6's bug instead:
//   - scan1: __launch_bounds__(512,2) -> 256-VGPR budget; weights (16 uint4)
//     pinned with asm (r7-verified technique). 256 blocks (1 batch row each).
//   - scan2: __launch_bounds__(256,1); 8 uint4 weights pinned. h2 out as bf16.
//   - xg GEMMs: r4's verified gemm_mfma (bf16 MFMA, 128x128, XOR-swizzled LDS).
//   - layer-3: bf16-input row GEMM + r5's 8-deep prefetch-ring scan.
// T=512, B=256, IN=97(pad128), H1=128, H2=64, H3=1.

#define T_TOT 512
#define BB    256
#define CH    128
#define NCH   4

typedef __attribute__((ext_vector_type(8))) short  short8v;   // 8 bf16
typedef __attribute__((ext_vector_type(4))) float  float4v;   // MFMA acc

// D += S0.bf16lo*S1.bf16lo + S0.bf16hi*S1.bf16hi  (VOP3P, verified r5/r6)
#define DOT2BF(acc, wu, hu) \
    asm("v_dot2_f32_bf16 %0, %1, %2, %0" : "+v"(acc) : "v"(wu), "v"(hu))

__device__ __forceinline__ float sigm(float x) {
    float e = __expf(-x);
    return __builtin_amdgcn_rcpf(1.0f + e);
}
__device__ __forceinline__ float tanh_(float x) {
    float e = __expf(2.0f * x);
    return 1.0f - 2.0f * __builtin_amdgcn_rcpf(1.0f + e);
}
__device__ __forceinline__ unsigned short f2bf(float x) {
    __hip_bfloat16 b = __float2bfloat16(x);
    return __builtin_bit_cast(unsigned short, b);
}
__device__ __forceinline__ float b2f(unsigned short u) {
    unsigned int x = (unsigned int)u << 16;
    return __builtin_bit_cast(float, x);
}

// ---------------------------------------------------------------------------
__global__ __launch_bounds__(256) void cvt_pad(
    const float* __restrict__ in, __hip_bfloat16* __restrict__ out, int R, int K)
{
    int total = R * 128;
    for (int idx = blockIdx.x * 256 + threadIdx.x; idx < total; idx += gridDim.x * 256) {
        int r = idx >> 7, c = idx & 127;
        float v = (c < K) ? in[(size_t)r * K + c] : 0.0f;
        out[idx] = __float2bfloat16(v);
    }
}
__global__ __launch_bounds__(256) void cvt_plain(
    const float* __restrict__ in, __hip_bfloat16* __restrict__ out, int n)
{
    int i = blockIdx.x * 256 + threadIdx.x;
    if (i < n) out[i] = __float2bfloat16(in[i]);
}
__global__ __launch_bounds__(256) void addvec(
    const float* __restrict__ a, const float* __restrict__ b, float* __restrict__ o, int n)
{
    int i = blockIdx.x * 256 + threadIdx.x;
    if (i < n) o[i] = a[i] + b[i];
}

// ---------------------------------------------------------------------------
// bf16 MFMA GEMM (r4, verified): C[M,N] = A[M,128] * W[N,128]^T + bias
// grid=(M/128, N/128), block=256.
// ---------------------------------------------------------------------------
__global__ __launch_bounds__(256) void gemm_mfma(
    const __hip_bfloat16* __restrict__ A,
    const __hip_bfloat16* __restrict__ W,
    const float* __restrict__ bias,
    float* __restrict__ C, int N)
{
    __shared__ __hip_bfloat16 At[128 * 128];   // 32 KB

    const int tid  = threadIdx.x;
    const int lane = tid & 63;
    const int wid  = tid >> 6;
    const int m0   = blockIdx.x * 128;
    const int n0   = blockIdx.y * 128;
    const int wr   = wid >> 1;
    const int wc   = wid & 1;

    short8v bfrag[4][4];  // [nf][kf]
    {
        const char* Wg = (const char*)W;
#pragma unroll
        for (int nf = 0; nf < 4; ++nf) {
            int row = n0 + wc * 64 + nf * 16 + (lane & 15);
#pragma unroll
            for (int kf = 0; kf < 4; ++kf) {
                int colb = (kf * 32 + (lane >> 4) * 8) * 2;
                bfrag[nf][kf] = *(const short8v*)(Wg + (size_t)row * 256 + colb);
            }
        }
    }
    {
        const char* Ag = (const char*)(A + (size_t)m0 * 128);
        char* As = (char*)At;
#pragma unroll
        for (int r2 = 0; r2 < 8; ++r2) {
            int off = r2 * 4096 + tid * 16;
            int row = off >> 8;
            int bir = off & 255;
            short8v v = *(const short8v*)(Ag + (size_t)row * 256 + bir);
            int sw = bir ^ ((row & 7) << 4);
            *(short8v*)(As + row * 256 + sw) = v;
        }
    }
    __syncthreads();

    float4v acc[4][4] = {};
#pragma unroll
    for (int kf = 0; kf < 4; ++kf) {
        short8v af[4];
#pragma unroll
        for (int mf = 0; mf < 4; ++mf) {
            int row   = wr * 64 + mf * 16 + (lane & 15);
            int kbyte = kf * 64 + (lane >> 4) * 16;
            int sw    = kbyte ^ ((row & 7) << 4);
            af[mf] = *(const short8v*)((const char*)At + row * 256 + sw);
        }
#pragma unroll
        for (int mf = 0; mf < 4; ++mf)
#pragma unroll
            for (int nf = 0; nf < 4; ++nf)
                acc[mf][nf] = __builtin_amdgcn_mfma_f32_16x16x32_bf16(
                    af[mf], bfrag[nf][kf], acc[mf][nf], 0, 0, 0);
    }

#pragma unroll
    for (int nf = 0; nf < 4; ++nf) {
        int col = n0 + wc * 64 + nf * 16 + (lane & 15);
        float bv = bias[col];
#pragma unroll
        for (int mf = 0; mf < 4; ++mf) {
            int rbase = m0 + wr * 64 + mf * 16 + (lane >> 4) * 4;
#pragma unroll
            for (int r = 0; r < 4; ++r)
                C[(size_t)(rbase + r) * N + col] = acc[mf][nf][r] + bv;
        }
    }
}

// ---------------------------------------------------------------------------
// scan1 (H=128): 256 blocks (1 batch row each) x 512 thr (8 waves, 2/SIMD).
// Thread n owns gate-row n: 128 bf16 weights = 16 uint4 = 64 VGPR, PINNED.
// launch_bounds(512,2) -> 256-VGPR budget (r6's spill was 8-wave target).
// h bf16-packed in LDS (wave-uniform broadcast b128 reads). 2 barriers/step.
// ---------------------------------------------------------------------------
__global__ __launch_bounds__(512, 2) void lstm_scan1(
    const float* __restrict__ xg,        // [Tc, BB, 512] f32, bias included
    const unsigned int* __restrict__ Wp, // [512 rows][64 uint] bf16-pairs
    __hip_bfloat16* __restrict__ hout,   // [Tc, BB, 128]
    float* __restrict__ hstate, float* __restrict__ cstate,
    int Tc, int first)
{
    const int n   = threadIdx.x;     // gate-row 0..511
    const int row = blockIdx.x;
    __shared__ unsigned int hbuf[2][64];   // 128 bf16, double-buffered
    __shared__ float g_lds[512];

    uint4 w[16];   // 64 VGPR of weights, static-indexed + pinned
    {
        const uint4* wr_ = (const uint4*)(Wp + (size_t)n * 64);
#pragma unroll
        for (int j = 0; j < 16; ++j) w[j] = wr_[j];
    }
#pragma unroll
    for (int j = 0; j < 16; ++j)
        asm volatile("" : "+v"(w[j].x), "+v"(w[j].y), "+v"(w[j].z), "+v"(w[j].w));

    float c = 0.0f, hf = 0.0f;
    if (n < 128) {
        c  = first ? 0.0f : cstate[row * 128 + n];
        hf = first ? 0.0f : hstate[row * 128 + n];
        ((unsigned short*)hbuf[0])[n] = f2bf(hf);
    }
    __syncthreads();

    const float* px = xg + (size_t)row * 512 + n;
    float xc = px[0];
    float xn = (Tc > 1) ? px[(size_t)BB * 512] : 0.0f;

    int cur = 0;
    for (int t = 0; t < Tc; ++t) {
        float a = xc;
        xc = xn;
        if (t + 2 < Tc) xn = px[(size_t)(t + 2) * BB * 512];

        const uint4* hb = (const uint4*)hbuf[cur];   // wave-uniform (broadcast)
#pragma unroll
        for (int j = 0; j < 16; ++j) {
            uint4 hv = hb[j];
            DOT2BF(a, w[j].x, hv.x); DOT2BF(a, w[j].y, hv.y);
            DOT2BF(a, w[j].z, hv.z); DOT2BF(a, w[j].w, hv.w);
        }
        g_lds[n] = a;
        __syncthreads();

        if (n < 128) {
            float i_ = sigm(g_lds[n]);
            float f_ = sigm(g_lds[n + 128]);
            float g_ = tanh_(g_lds[n + 256]);
            float o_ = sigm(g_lds[n + 384]);
            c  = fmaf(f_, c, i_ * g_);
            hf = o_ * tanh_(c);
            unsigned short hb16 = f2bf(hf);
            ((unsigned short*)hbuf[cur ^ 1])[n] = hb16;
            ((unsigned short*)hout)[((size_t)t * BB + row) * 128 + n] = hb16;
        }
        cur ^= 1;
        __syncthreads();
    }
    if (n < 128) {
        cstate[row * 128 + n] = c;
        hstate[row * 128 + n] = hf;
    }
}

// ---------------------------------------------------------------------------
// scan2 (H=64): 256 blocks x 256 thr (4 waves, 1/SIMD, bounds(256,1)).
// Thread n owns gate-row n: 64 bf16 = 8 uint4 = 32 VGPR, pinned.
// h2 output bf16 (feeds bf16 layer-3 GEMM).
// ---------------------------------------------------------------------------
__global__ __launch_bounds__(256, 1) void lstm_scan2(
    const float* __restrict__ xg,        // [Tc, BB, 256]
    const unsigned int* __restrict__ Wp, // [256 rows][32 uint] bf16-pairs
    __hip_bfloat16* __restrict__ hout,   // [Tc, BB, 64] bf16
    float* __restrict__ hstate, float* __restrict__ cstate,
    int Tc, int first)
{
    const int n   = threadIdx.x;   // gate-row 0..255
    const int row = blockIdx.x;
    __shared__ unsigned int hbuf[2][32];
    __shared__ float g_lds[256];

    uint4 w[8];
    {
        const uint4* wr_ = (const uint4*)(Wp + (size_t)n * 32);
#pragma unroll
        for (int j = 0; j < 8; ++j) w[j] = wr_[j];
    }
#pragma unroll
    for (int j = 0; j < 8; ++j)
        asm volatile("" : "+v"(w[j].x), "+v"(w[j].y), "+v"(w[j].z), "+v"(w[j].w));

    float c = 0.0f, hf = 0.0f;
    if (n < 64) {
        c  = first ? 0.0f : cstate[row * 64 + n];
        hf = first ? 0.0f : hstate[row * 64 + n];
        ((unsigned short*)hbuf[0])[n] = f2bf(hf);
    }
    __syncthreads();

    const float* px = xg + (size_t)row * 256 + n;
    float xc = px[0];
    float xn = (Tc > 1) ? px[(size_t)BB * 256] : 0.0f;

    int cur = 0;
    for (int t = 0; t < Tc; ++t) {
        float a = xc;
        xc = xn;
        if (t + 2 < Tc) xn = px[(size_t)(t + 2) * BB * 256];

        const uint4* hb = (const uint4*)hbuf[cur];
#pragma unroll
        for (int j = 0; j < 8; ++j) {
            uint4 hv = hb[j];
            DOT2BF(a, w[j].x, hv.x); DOT2BF(a, w[j].y, hv.y);
            DOT2BF(a, w[j].z, hv.z); DOT2BF(a, w[j].w, hv.w);
        }
        g_lds[n] = a;
        __syncthreads();

        if (n < 64) {
            float i_ = sigm(g_lds[n]);
            float f_ = sigm(g_lds[n + 64]);
            float g_ = tanh_(g_lds[n + 128]);
            float o_ = sigm(g_lds[n + 192]);
            c  = fmaf(f_, c, i_ * g_);
            hf = o_ * tanh_(c);
            unsigned short hb16 = f2bf(hf);
            ((unsigned short*)hbuf[cur ^ 1])[n] = hb16;
            ((unsigned short*)hout)[((size_t)t * BB + row) * 64 + n] = hb16;
        }
        cur ^= 1;
        __syncthreads();
    }
    if (n < 64) {
        cstate[row * 64 + n] = c;
        hstate[row * 64 + n] = hf;
    }
}

// ---------------------------------------------------------------------------
// Layer-3 input GEMM, bf16 X: out[m,0..3] = sum_k X[m,k]*W[n,k] + b
// ---------------------------------------------------------------------------
__global__ __launch_bounds__(256) void gemm_xg3b(
    const __hip_bfloat16* __restrict__ X,  // [M, 64] bf16
    const float* __restrict__ W,           // [4, 64] f32
    const float* __restrict__ b1, const float* __restrict__ b2,
    float* __restrict__ out)               // [M, 4]
{
    __shared__ __align__(16) float ws4[4][64];
    __shared__ float bb[4];
    const int tid = threadIdx.x;
    {
        const int nn = tid >> 6, kk = tid & 63;
        ws4[nn][kk] = W[nn * 64 + kk];
    }
    if (tid < 4) bb[tid] = b1[tid] + b2[tid];
    __syncthreads();

    const int m = blockIdx.x * 256 + tid;
    const uint4* xr = reinterpret_cast<const uint4*>(X + (size_t)m * 64);
    float a0 = bb[0], a1 = bb[1], a2 = bb[2], a3 = bb[3];
#pragma unroll
    for (int kk = 0; kk < 8; ++kk) {       // 8 bf16 per uint4
        uint4 v = xr[kk];
        float xf[8];
        xf[0] = b2f((unsigned short)(v.x & 0xffff));
        xf[1] = b2f((unsigned short)(v.x >> 16));
        xf[2] = b2f((unsigned short)(v.y & 0xffff));
        xf[3] = b2f((unsigned short)(v.y >> 16));
        xf[4] = b2f((unsigned short)(v.z & 0xffff));
        xf[5] = b2f((unsigned short)(v.z >> 16));
        xf[6] = b2f((unsigned short)(v.w & 0xffff));
        xf[7] = b2f((unsigned short)(v.w >> 16));
#pragma unroll
        for (int j = 0; j < 8; ++j) {
            int k = kk * 8 + j;
            a0 = fmaf(xf[j], ws4[0][k], a0);
            a1 = fmaf(xf[j], ws4[1][k], a1);
            a2 = fmaf(xf[j], ws4[2][k], a2);
            a3 = fmaf(xf[j], ws4[3][k], a3);
        }
    }
    float4 o; o.x = a0; o.y = a1; o.z = a2; o.w = a3;
    *reinterpret_cast<float4*>(&out[(size_t)m * 4]) = o;
}

// ---------------------------------------------------------------------------
// Layer-3 scan: 8-deep static prefetch ring (r5, verified).
// ---------------------------------------------------------------------------
__global__ __launch_bounds__(256) void lstm_scan3(
    const float* __restrict__ xg,   // [T, B, 4]
    const float* __restrict__ Whh,  // [4, 1]
    float* __restrict__ out,        // [T, B]
    int T)
{
    const int b = threadIdx.x;
    const float w0 = Whh[0], w1 = Whh[1], w2 = Whh[2], w3 = Whh[3];
    float h = 0.0f, c = 0.0f;
    const float4* p = reinterpret_cast<const float4*>(xg) + b;

    float4 cur[8], nxt[8];
#pragma unroll
    for (int j = 0; j < 8; ++j) cur[j] = p[(size_t)j * BB];

    for (int t0 = 0; t0 < T; t0 += 8) {
#pragma unroll
        for (int j = 0; j < 8; ++j) {
            int tt = t0 + 8 + j;
            if (tt < T) nxt[j] = p[(size_t)tt * BB];
        }
#pragma unroll
        for (int j = 0; j < 8; ++j) {
            float4 g4 = cur[j];
            float gi = fmaf(h, w0, g4.x);
            float gf = fmaf(h, w1, g4.y);
            float gg = fmaf(h, w2, g4.z);
            float go = fmaf(h, w3, g4.w);
            float i_ = sigm(gi);
            float f_ = sigm(gf);
            float g_ = tanh_(gg);
            float o_ = sigm(go);
            c = fmaf(f_, c, i_ * g_);
            h = o_ * tanh_(c);
            out[(size_t)(t0 + j) * BB + b] = h;
        }
#pragma unroll
        for (int j = 0; j < 8; ++j) cur[j] = nxt[j];
    }
}

// ---------------------------------------------------------------------------
extern "C" void kernel_launch(void* const* d_in, const int* in_sizes, int n_in,
                              void* d_out, int out_size, void* d_ws, size_t ws_size,
                              hipStream_t stream) {
    const float* x    = (const float*)d_in[0];
    const float* Wih1 = (const float*)d_in[1];
    const float* Whh1 = (const float*)d_in[2];
    const float* bih1 = (const float*)d_in[3];
    const float* bhh1 = (const float*)d_in[4];
    const float* Wih2 = (const float*)d_in[5];
    const float* Whh2 = (const float*)d_in[6];
    const float* bih2 = (const float*)d_in[7];
    const float* bhh2 = (const float*)d_in[8];
    const float* Wih3 = (const float*)d_in[9];
    const float* Whh3 = (const float*)d_in[10];
    const float* bih3 = (const float*)d_in[11];
    const float* bhh3 = (const float*)d_in[12];
    float* out = (float*)d_out;

    char* ws = (char*)d_ws;
    // Workspace layout, ~187.4 MB total:
    float*          xg1c  = (float*)(ws + 0);                   // [CH,B,512] f32 = 67,108,864
    float*          xg2c  = (float*)(ws + 67108864);            // [CH,B,256] f32 = 33,554,432
    __hip_bfloat16* xb    = (__hip_bfloat16*)(ws + 100663296);  // [T,B,128] bf16 = 33,554,432
    __hip_bfloat16* h1b   = (__hip_bfloat16*)(ws + 134217728);  // [T,B,128] bf16 = 33,554,432
    __hip_bfloat16* h2bb  = (__hip_bfloat16*)(ws + 167772160);  // [T,B,64]  bf16 = 16,777,216
    float*          xg3   = (float*)(ws + 184549376);           // [T,B,4]   f32  =  2,097,152
    __hip_bfloat16* wb1   = (__hip_bfloat16*)(ws + 186646528);  // [512,128] =   131,072
    __hip_bfloat16* whb1  = (__hip_bfloat16*)(ws + 186777600);  // [512,128] =   131,072
    __hip_bfloat16* wb2   = (__hip_bfloat16*)(ws + 186908672);  // [256,128] =    65,536
    __hip_bfloat16* whb2  = (__hip_bfloat16*)(ws + 186974208);  // [256,64]  =    32,768
    float*          bias1 = (float*)(ws + 187006976);           //     2,048
    float*          bias2 = (float*)(ws + 187009024);           //     1,024
    float*          bias3 = (float*)(ws + 187010048);           //        64
    float*          st1h  = (float*)(ws + 187010112);           // [B,128] f32
    float*          st1c  = (float*)(ws + 187141184);
    float*          st2h  = (float*)(ws + 187272256);           // [B,64] f32
    float*          st2c  = (float*)(ws + 187337792);

    // ---- P0: conversions / bias prep ----
    cvt_pad<<<4096, 256, 0, stream>>>(x, xb, T_TOT * BB, 97);
    cvt_pad<<<256, 256, 0, stream>>>(Wih1, wb1, 512, 97);
    cvt_plain<<<256, 256, 0, stream>>>(Whh1, whb1, 512 * 128);
    cvt_plain<<<128, 256, 0, stream>>>(Wih2, wb2, 256 * 128);
    cvt_plain<<<64, 256, 0, stream>>>(Whh2, whb2, 256 * 64);
    addvec<<<2, 256, 0, stream>>>(bih1, bhh1, bias1, 512);
    addvec<<<1, 256, 0, stream>>>(bih2, bhh2, bias2, 256);

    // ---- Layer 1 (chunked over T) ----
    for (int c0 = 0; c0 < NCH; ++c0) {
        gemm_mfma<<<dim3(CH * BB / 128, 512 / 128), 256, 0, stream>>>(
            xb + (size_t)c0 * CH * BB * 128, wb1, bias1, xg1c, 512);
        lstm_scan1<<<BB, 512, 0, stream>>>(
            xg1c, (const unsigned int*)whb1,
            h1b + (size_t)c0 * CH * BB * 128, st1h, st1c, CH, c0 == 0);
    }
    // ---- Layer 2 (chunked over T) ----
    for (int c0 = 0; c0 < NCH; ++c0) {
        gemm_mfma<<<dim3(CH * BB / 128, 256 / 128), 256, 0, stream>>>(
            h1b + (size_t)c0 * CH * BB * 128, wb2, bias2, xg2c, 256);
        lstm_scan2<<<BB, 256, 0, stream>>>(
            xg2c, (const unsigned int*)whb2,
            h2bb + (size_t)c0 * CH * BB * 64, st2h, st2c, CH, c0 == 0);
    }
    // ---- Layer 3 ----
    gemm_xg3b<<<T_TOT * BB / 256, 256, 0, stream>>>(h2bb, Wih3, bih3, bhh3, xg3);
    lstm_scan3<<<1, 256, 0, stream>>>(xg3, Whh3, out, T_TOT);
}

// Round 13
// 837.667 us; speedup vs baseline: 1.1871x; 1.0916x over previous
//
#include <hip/hip_runtime.h>
#include <hip/hip_bf16.h>

// 3-layer stacked LSTM forward (eval). Round 13 = Round 12 + FORCED weight
// residency in the scans.
//  r12 evidence: scan1 VGPR_Count=44 (same as r6) -> the pre-loop asm pin did
//  NOT stop the allocator from sinking the 64-VGPR weight array into the loop
//  (it chases 8 waves/SIMD; dot2 needs VGPRs, unlike r7's MFMA/AGPR case).
//  Fixes:
//   (a) amdgpu_waves_per_eu(2,2) on scan1 / (1,1) on scan2: allocator target =
//       minimum occupancy -> 256/512-VGPR budget, no reason to sink loads.
//   (b) weight pin moved INSIDE the step loop: "+v" asm makes the weights
//       loop-carried through an opaque asm -> loads cannot be rematerialized
//       in-loop. Tell: scan1 VGPR >= 110.
//  Everything else identical to r12 (MFMA xg GEMMs, bf16 h buffers, scan3 ring).
// T=512, B=256, IN=97(pad128), H1=128, H2=64, H3=1.

#define T_TOT 512
#define BB    256
#define CH    128
#define NCH   4

typedef __attribute__((ext_vector_type(8))) short  short8v;   // 8 bf16
typedef __attribute__((ext_vector_type(4))) float  float4v;   // MFMA acc

// D += S0.bf16lo*S1.bf16lo + S0.bf16hi*S1.bf16hi  (VOP3P, verified r5/r6)
#define DOT2BF(acc, wu, hu) \
    asm("v_dot2_f32_bf16 %0, %1, %2, %0" : "+v"(acc) : "v"(wu), "v"(hu))

__device__ __forceinline__ float sigm(float x) {
    float e = __expf(-x);
    return __builtin_amdgcn_rcpf(1.0f + e);
}
__device__ __forceinline__ float tanh_(float x) {
    float e = __expf(2.0f * x);
    return 1.0f - 2.0f * __builtin_amdgcn_rcpf(1.0f + e);
}
__device__ __forceinline__ unsigned short f2bf(float x) {
    __hip_bfloat16 b = __float2bfloat16(x);
    return __builtin_bit_cast(unsigned short, b);
}
__device__ __forceinline__ float b2f(unsigned short u) {
    unsigned int x = (unsigned int)u << 16;
    return __builtin_bit_cast(float, x);
}

// ---------------------------------------------------------------------------
__global__ __launch_bounds__(256) void cvt_pad(
    const float* __restrict__ in, __hip_bfloat16* __restrict__ out, int R, int K)
{
    int total = R * 128;
    for (int idx = blockIdx.x * 256 + threadIdx.x; idx < total; idx += gridDim.x * 256) {
        int r = idx >> 7, c = idx & 127;
        float v = (c < K) ? in[(size_t)r * K + c] : 0.0f;
        out[idx] = __float2bfloat16(v);
    }
}
__global__ __launch_bounds__(256) void cvt_plain(
    const float* __restrict__ in, __hip_bfloat16* __restrict__ out, int n)
{
    int i = blockIdx.x * 256 + threadIdx.x;
    if (i < n) out[i] = __float2bfloat16(in[i]);
}
__global__ __launch_bounds__(256) void addvec(
    const float* __restrict__ a, const float* __restrict__ b, float* __restrict__ o, int n)
{
    int i = blockIdx.x * 256 + threadIdx.x;
    if (i < n) o[i] = a[i] + b[i];
}

// ---------------------------------------------------------------------------
// bf16 MFMA GEMM (r4, verified): C[M,N] = A[M,128] * W[N,128]^T + bias
// ---------------------------------------------------------------------------
__global__ __launch_bounds__(256) void gemm_mfma(
    const __hip_bfloat16* __restrict__ A,
    const __hip_bfloat16* __restrict__ W,
    const float* __restrict__ bias,
    float* __restrict__ C, int N)
{
    __shared__ __hip_bfloat16 At[128 * 128];   // 32 KB

    const int tid  = threadIdx.x;
    const int lane = tid & 63;
    const int wid  = tid >> 6;
    const int m0   = blockIdx.x * 128;
    const int n0   = blockIdx.y * 128;
    const int wr   = wid >> 1;
    const int wc   = wid & 1;

    short8v bfrag[4][4];  // [nf][kf]
    {
        const char* Wg = (const char*)W;
#pragma unroll
        for (int nf = 0; nf < 4; ++nf) {
            int row = n0 + wc * 64 + nf * 16 + (lane & 15);
#pragma unroll
            for (int kf = 0; kf < 4; ++kf) {
                int colb = (kf * 32 + (lane >> 4) * 8) * 2;
                bfrag[nf][kf] = *(const short8v*)(Wg + (size_t)row * 256 + colb);
            }
        }
    }
    {
        const char* Ag = (const char*)(A + (size_t)m0 * 128);
        char* As = (char*)At;
#pragma unroll
        for (int r2 = 0; r2 < 8; ++r2) {
            int off = r2 * 4096 + tid * 16;
            int row = off >> 8;
            int bir = off & 255;
            short8v v = *(const short8v*)(Ag + (size_t)row * 256 + bir);
            int sw = bir ^ ((row & 7) << 4);
            *(short8v*)(As + row * 256 + sw) = v;
        }
    }
    __syncthreads();

    float4v acc[4][4] = {};
#pragma unroll
    for (int kf = 0; kf < 4; ++kf) {
        short8v af[4];
#pragma unroll
        for (int mf = 0; mf < 4; ++mf) {
            int row   = wr * 64 + mf * 16 + (lane & 15);
            int kbyte = kf * 64 + (lane >> 4) * 16;
            int sw    = kbyte ^ ((row & 7) << 4);
            af[mf] = *(const short8v*)((const char*)At + row * 256 + sw);
        }
#pragma unroll
        for (int mf = 0; mf < 4; ++mf)
#pragma unroll
            for (int nf = 0; nf < 4; ++nf)
                acc[mf][nf] = __builtin_amdgcn_mfma_f32_16x16x32_bf16(
                    af[mf], bfrag[nf][kf], acc[mf][nf], 0, 0, 0);
    }

#pragma unroll
    for (int nf = 0; nf < 4; ++nf) {
        int col = n0 + wc * 64 + nf * 16 + (lane & 15);
        float bv = bias[col];
#pragma unroll
        for (int mf = 0; mf < 4; ++mf) {
            int rbase = m0 + wr * 64 + mf * 16 + (lane >> 4) * 4;
#pragma unroll
            for (int r = 0; r < 4; ++r)
                C[(size_t)(rbase + r) * N + col] = acc[mf][nf][r] + bv;
        }
    }
}

// ---------------------------------------------------------------------------
// scan1 (H=128): 256 blocks x 512 thr (8 waves). Thread n owns gate-row n:
// 128 bf16 weights = 16 uint4 = 64 VGPR, held resident by (a) waves_per_eu(2,2)
// occupancy pin and (b) in-loop asm pin (loop-carried opaque redef).
// ---------------------------------------------------------------------------
__global__ __launch_bounds__(512)
__attribute__((amdgpu_waves_per_eu(2, 2)))
void lstm_scan1(
    const float* __restrict__ xg,        // [Tc, BB, 512] f32, bias included
    const unsigned int* __restrict__ Wp, // [512 rows][64 uint] bf16-pairs
    __hip_bfloat16* __restrict__ hout,   // [Tc, BB, 128]
    float* __restrict__ hstate, float* __restrict__ cstate,
    int Tc, int first)
{
    const int n   = threadIdx.x;     // gate-row 0..511
    const int row = blockIdx.x;
    __shared__ unsigned int hbuf[2][64];   // 128 bf16, double-buffered
    __shared__ float g_lds[512];

    uint4 w[16];   // 64 VGPR of weights, static-indexed
    {
        const uint4* wr_ = (const uint4*)(Wp + (size_t)n * 64);
#pragma unroll
        for (int j = 0; j < 16; ++j) w[j] = wr_[j];
    }

    float c = 0.0f, hf = 0.0f;
    if (n < 128) {
        c  = first ? 0.0f : cstate[row * 128 + n];
        hf = first ? 0.0f : hstate[row * 128 + n];
        ((unsigned short*)hbuf[0])[n] = f2bf(hf);
    }
    __syncthreads();

    const float* px = xg + (size_t)row * 512 + n;
    float xc = px[0];
    float xn = (Tc > 1) ? px[(size_t)BB * 512] : 0.0f;

    int cur = 0;
    for (int t = 0; t < Tc; ++t) {
        // In-loop pin: weights are loop-carried through opaque asm -> the
        // loads cannot be sunk/rematerialized inside the loop.
#pragma unroll
        for (int j = 0; j < 16; ++j)
            asm volatile("" : "+v"(w[j].x), "+v"(w[j].y), "+v"(w[j].z), "+v"(w[j].w));

        float a = xc;
        xc = xn;
        if (t + 2 < Tc) xn = px[(size_t)(t + 2) * BB * 512];

        const uint4* hb = (const uint4*)hbuf[cur];   // wave-uniform (broadcast)
#pragma unroll
        for (int j = 0; j < 16; ++j) {
            uint4 hv = hb[j];
            DOT2BF(a, w[j].x, hv.x); DOT2BF(a, w[j].y, hv.y);
            DOT2BF(a, w[j].z, hv.z); DOT2BF(a, w[j].w, hv.w);
        }
        g_lds[n] = a;
        __syncthreads();

        if (n < 128) {
            float i_ = sigm(g_lds[n]);
            float f_ = sigm(g_lds[n + 128]);
            float g_ = tanh_(g_lds[n + 256]);
            float o_ = sigm(g_lds[n + 384]);
            c  = fmaf(f_, c, i_ * g_);
            hf = o_ * tanh_(c);
            unsigned short hb16 = f2bf(hf);
            ((unsigned short*)hbuf[cur ^ 1])[n] = hb16;
            ((unsigned short*)hout)[((size_t)t * BB + row) * 128 + n] = hb16;
        }
        cur ^= 1;
        __syncthreads();
    }
    if (n < 128) {
        cstate[row * 128 + n] = c;
        hstate[row * 128 + n] = hf;
    }
}

// ---------------------------------------------------------------------------
// scan2 (H=64): 256 blocks x 256 thr (4 waves). 8 uint4 = 32 VGPR weights,
// same residency enforcement. h2 output bf16.
// ---------------------------------------------------------------------------
__global__ __launch_bounds__(256)
__attribute__((amdgpu_waves_per_eu(1, 1)))
void lstm_scan2(
    const float* __restrict__ xg,        // [Tc, BB, 256]
    const unsigned int* __restrict__ Wp, // [256 rows][32 uint] bf16-pairs
    __hip_bfloat16* __restrict__ hout,   // [Tc, BB, 64] bf16
    float* __restrict__ hstate, float* __restrict__ cstate,
    int Tc, int first)
{
    const int n   = threadIdx.x;   // gate-row 0..255
    const int row = blockIdx.x;
    __shared__ unsigned int hbuf[2][32];
    __shared__ float g_lds[256];

    uint4 w[8];
    {
        const uint4* wr_ = (const uint4*)(Wp + (size_t)n * 32);
#pragma unroll
        for (int j = 0; j < 8; ++j) w[j] = wr_[j];
    }

    float c = 0.0f, hf = 0.0f;
    if (n < 64) {
        c  = first ? 0.0f : cstate[row * 64 + n];
        hf = first ? 0.0f : hstate[row * 64 + n];
        ((unsigned short*)hbuf[0])[n] = f2bf(hf);
    }
    __syncthreads();

    const float* px = xg + (size_t)row * 256 + n;
    float xc = px[0];
    float xn = (Tc > 1) ? px[(size_t)BB * 256] : 0.0f;

    int cur = 0;
    for (int t = 0; t < Tc; ++t) {
#pragma unroll
        for (int j = 0; j < 8; ++j)
            asm volatile("" : "+v"(w[j].x), "+v"(w[j].y), "+v"(w[j].z), "+v"(w[j].w));

        float a = xc;
        xc = xn;
        if (t + 2 < Tc) xn = px[(size_t)(t + 2) * BB * 256];

        const uint4* hb = (const uint4*)hbuf[cur];
#pragma unroll
        for (int j = 0; j < 8; ++j) {
            uint4 hv = hb[j];
            DOT2BF(a, w[j].x, hv.x); DOT2BF(a, w[j].y, hv.y);
            DOT2BF(a, w[j].z, hv.z); DOT2BF(a, w[j].w, hv.w);
        }
        g_lds[n] = a;
        __syncthreads();

        if (n < 64) {
            float i_ = sigm(g_lds[n]);
            float f_ = sigm(g_lds[n + 64]);
            float g_ = tanh_(g_lds[n + 128]);
            float o_ = sigm(g_lds[n + 192]);
            c  = fmaf(f_, c, i_ * g_);
            hf = o_ * tanh_(c);
            unsigned short hb16 = f2bf(hf);
            ((unsigned short*)hbuf[cur ^ 1])[n] = hb16;
            ((unsigned short*)hout)[((size_t)t * BB + row) * 64 + n] = hb16;
        }
        cur ^= 1;
        __syncthreads();
    }
    if (n < 64) {
        cstate[row * 64 + n] = c;
        hstate[row * 64 + n] = hf;
    }
}

// ---------------------------------------------------------------------------
// Layer-3 input GEMM, bf16 X: out[m,0..3] = sum_k X[m,k]*W[n,k] + b
// ---------------------------------------------------------------------------
__global__ __launch_bounds__(256) void gemm_xg3b(
    const __hip_bfloat16* __restrict__ X,  // [M, 64] bf16
    const float* __restrict__ W,           // [4, 64] f32
    const float* __restrict__ b1, const float* __restrict__ b2,
    float* __restrict__ out)               // [M, 4]
{
    __shared__ __align__(16) float ws4[4][64];
    __shared__ float bb[4];
    const int tid = threadIdx.x;
    {
        const int nn = tid >> 6, kk = tid & 63;
        ws4[nn][kk] = W[nn * 64 + kk];
    }
    if (tid < 4) bb[tid] = b1[tid] + b2[tid];
    __syncthreads();

    const int m = blockIdx.x * 256 + tid;
    const uint4* xr = reinterpret_cast<const uint4*>(X + (size_t)m * 64);
    float a0 = bb[0], a1 = bb[1], a2 = bb[2], a3 = bb[3];
#pragma unroll
    for (int kk = 0; kk < 8; ++kk) {       // 8 bf16 per uint4
        uint4 v = xr[kk];
        float xf[8];
        xf[0] = b2f((unsigned short)(v.x & 0xffff));
        xf[1] = b2f((unsigned short)(v.x >> 16));
        xf[2] = b2f((unsigned short)(v.y & 0xffff));
        xf[3] = b2f((unsigned short)(v.y >> 16));
        xf[4] = b2f((unsigned short)(v.z & 0xffff));
        xf[5] = b2f((unsigned short)(v.z >> 16));
        xf[6] = b2f((unsigned short)(v.w & 0xffff));
        xf[7] = b2f((unsigned short)(v.w >> 16));
#pragma unroll
        for (int j = 0; j < 8; ++j) {
            int k = kk * 8 + j;
            a0 = fmaf(xf[j], ws4[0][k], a0);
            a1 = fmaf(xf[j], ws4[1][k], a1);
            a2 = fmaf(xf[j], ws4[2][k], a2);
            a3 = fmaf(xf[j], ws4[3][k], a3);
        }
    }
    float4 o; o.x = a0; o.y = a1; o.z = a2; o.w = a3;
    *reinterpret_cast<float4*>(&out[(size_t)m * 4]) = o;
}

// ---------------------------------------------------------------------------
// Layer-3 scan: 8-deep static prefetch ring (r5, verified).
// ---------------------------------------------------------------------------
__global__ __launch_bounds__(256) void lstm_scan3(
    const float* __restrict__ xg,   // [T, B, 4]
    const float* __restrict__ Whh,  // [4, 1]
    float* __restrict__ out,        // [T, B]
    int T)
{
    const int b = threadIdx.x;
    const float w0 = Whh[0], w1 = Whh[1], w2 = Whh[2], w3 = Whh[3];
    float h = 0.0f, c = 0.0f;
    const float4* p = reinterpret_cast<const float4*>(xg) + b;

    float4 cur[8], nxt[8];
#pragma unroll
    for (int j = 0; j < 8; ++j) cur[j] = p[(size_t)j * BB];

    for (int t0 = 0; t0 < T; t0 += 8) {
#pragma unroll
        for (int j = 0; j < 8; ++j) {
            int tt = t0 + 8 + j;
            if (tt < T) nxt[j] = p[(size_t)tt * BB];
        }
#pragma unroll
        for (int j = 0; j < 8; ++j) {
            float4 g4 = cur[j];
            float gi = fmaf(h, w0, g4.x);
            float gf = fmaf(h, w1, g4.y);
            float gg = fmaf(h, w2, g4.z);
            float go = fmaf(h, w3, g4.w);
            float i_ = sigm(gi);
            float f_ = sigm(gf);
            float g_ = tanh_(gg);
            float o_ = sigm(go);
            c = fmaf(f_, c, i_ * g_);
            h = o_ * tanh_(c);
            out[(size_t)(t0 + j) * BB + b] = h;
        }
#pragma unroll
        for (int j = 0; j < 8; ++j) cur[j] = nxt[j];
    }
}

// ---------------------------------------------------------------------------
extern "C" void kernel_launch(void* const* d_in, const int* in_sizes, int n_in,
                              void* d_out, int out_size, void* d_ws, size_t ws_size,
                              hipStream_t stream) {
    const float* x    = (const float*)d_in[0];
    const float* Wih1 = (const float*)d_in[1];
    const float* Whh1 = (const float*)d_in[2];
    const float* bih1 = (const float*)d_in[3];
    const float* bhh1 = (const float*)d_in[4];
    const float* Wih2 = (const float*)d_in[5];
    const float* Whh2 = (const float*)d_in[6];
    const float* bih2 = (const float*)d_in[7];
    const float* bhh2 = (const float*)d_in[8];
    const float* Wih3 = (const float*)d_in[9];
    const float* Whh3 = (const float*)d_in[10];
    const float* bih3 = (const float*)d_in[11];
    const float* bhh3 = (const float*)d_in[12];
    float* out = (float*)d_out;

    char* ws = (char*)d_ws;
    // Workspace layout, ~187.4 MB total:
    float*          xg1c  = (float*)(ws + 0);                   // [CH,B,512] f32 = 67,108,864
    float*          xg2c  = (float*)(ws + 67108864);            // [CH,B,256] f32 = 33,554,432
    __hip_bfloat16* xb    = (__hip_bfloat16*)(ws + 100663296);  // [T,B,128] bf16 = 33,554,432
    __hip_bfloat16* h1b   = (__hip_bfloat16*)(ws + 134217728);  // [T,B,128] bf16 = 33,554,432
    __hip_bfloat16* h2bb  = (__hip_bfloat16*)(ws + 167772160);  // [T,B,64]  bf16 = 16,777,216
    float*          xg3   = (float*)(ws + 184549376);           // [T,B,4]   f32  =  2,097,152
    __hip_bfloat16* wb1   = (__hip_bfloat16*)(ws + 186646528);  // [512,128] =   131,072
    __hip_bfloat16* whb1  = (__hip_bfloat16*)(ws + 186777600);  // [512,128] =   131,072
    __hip_bfloat16* wb2   = (__hip_bfloat16*)(ws + 186908672);  // [256,128] =    65,536
    __hip_bfloat16* whb2  = (__hip_bfloat16*)(ws + 186974208);  // [256,64]  =    32,768
    float*          bias1 = (float*)(ws + 187006976);           //     2,048
    float*          bias2 = (float*)(ws + 187009024);           //     1,024
    float*          bias3 = (float*)(ws + 187010048);           //        64
    float*          st1h  = (float*)(ws + 187010112);           // [B,128] f32
    float*          st1c  = (float*)(ws + 187141184);
    float*          st2h  = (float*)(ws + 187272256);           // [B,64] f32
    float*          st2c  = (float*)(ws + 187337792);

    // ---- P0: conversions / bias prep ----
    cvt_pad<<<4096, 256, 0, stream>>>(x, xb, T_TOT * BB, 97);
    cvt_pad<<<256, 256, 0, stream>>>(Wih1, wb1, 512, 97);
    cvt_plain<<<256, 256, 0, stream>>>(Whh1, whb1, 512 * 128);
    cvt_plain<<<128, 256, 0, stream>>>(Wih2, wb2, 256 * 128);
    cvt_plain<<<64, 256, 0, stream>>>(Whh2, whb2, 256 * 64);
    addvec<<<2, 256, 0, stream>>>(bih1, bhh1, bias1, 512);
    addvec<<<1, 256, 0, stream>>>(bih2, bhh2, bias2, 256);

    // ---- Layer 1 (chunked over T) ----
    for (int c0 = 0; c0 < NCH; ++c0) {
        gemm_mfma<<<dim3(CH * BB / 128, 512 / 128), 256, 0, stream>>>(
            xb + (size_t)c0 * CH * BB * 128, wb1, bias1, xg1c, 512);
        lstm_scan1<<<BB, 512, 0, stream>>>(
            xg1c, (const unsigned int*)whb1,
            h1b + (size_t)c0 * CH * BB * 128, st1h, st1c, CH, c0 == 0);
    }
    // ---- Layer 2 (chunked over T) ----
    for (int c0 = 0; c0 < NCH; ++c0) {
        gemm_mfma<<<dim3(CH * BB / 128, 256 / 128), 256, 0, stream>>>(
            h1b + (size_t)c0 * CH * BB * 128, wb2, bias2, xg2c, 256);
        lstm_scan2<<<BB, 256, 0, stream>>>(
            xg2c, (const unsigned int*)whb2,
            h2bb + (size_t)c0 * CH * BB * 64, st2h, st2c, CH, c0 == 0);
    }
    // ---- Layer 3 ----
    gemm_xg3b<<<T_TOT * BB / 256, 256, 0, stream>>>(h2bb, Wih3, bih3, bhh3, xg3);
    lstm_scan3<<<1, 256, 0, stream>>>(xg3, Whh3, out, T_TOT);
}